// Round 1
// baseline (1875.522 us; speedup 1.0000x reference)
//
#include <hip/hip_runtime.h>
#include <hip/hip_bf16.h>

#define F_IN 1433
#define HID  64
#define C14  14

// ---------------- CSR build ----------------

__global__ void k_zero_int(int* __restrict__ p, int n) {
    int i = blockIdx.x * 256 + threadIdx.x;
    if (i < n) p[i] = 0;
}

__global__ void k_hist(const int* __restrict__ dst, int* __restrict__ cnt, int E) {
    int e = blockIdx.x * 256 + threadIdx.x;
    if (e < E) atomicAdd(&cnt[dst[e]], 1);
}

__global__ void k_dinv(const int* __restrict__ cnt, float* __restrict__ dinv, int n) {
    int i = blockIdx.x * 256 + threadIdx.x;
    if (i < n) dinv[i] = rsqrtf((float)cnt[i] + 1.0f);  // +1 self-loop; deg>=1 always
}

__global__ __launch_bounds__(1024) void k_scan1(const int* __restrict__ cnt,
                                                int* __restrict__ excl,
                                                int* __restrict__ bsum, int n) {
    __shared__ int sd[1024];
    int tid = threadIdx.x;
    int g = blockIdx.x * 1024 + tid;
    int v = (g < n) ? cnt[g] : 0;
    sd[tid] = v;
    __syncthreads();
    for (int off = 1; off < 1024; off <<= 1) {
        int t = (tid >= off) ? sd[tid - off] : 0;
        __syncthreads();
        sd[tid] += t;
        __syncthreads();
    }
    if (g < n) excl[g] = sd[tid] - v;          // block-local exclusive
    if (tid == 1023) bsum[blockIdx.x] = sd[1023];
}

__global__ __launch_bounds__(128) void k_scan2(const int* __restrict__ bsum,
                                               int* __restrict__ boff, int nb) {
    __shared__ int sd[128];
    int tid = threadIdx.x;
    int v = (tid < nb) ? bsum[tid] : 0;
    sd[tid] = v;
    __syncthreads();
    for (int off = 1; off < 128; off <<= 1) {
        int t = (tid >= off) ? sd[tid - off] : 0;
        __syncthreads();
        sd[tid] += t;
        __syncthreads();
    }
    if (tid < nb) boff[tid] = sd[tid] - v;
}

__global__ __launch_bounds__(1024) void k_scan3(int* __restrict__ rowst,
                                                const int* __restrict__ boff,
                                                int* __restrict__ fill, int n, int E) {
    int tid = threadIdx.x;
    int g = blockIdx.x * 1024 + tid;
    if (g < n) {
        int v = rowst[g] + boff[blockIdx.x];
        rowst[g] = v;
        fill[g] = v;
    }
    if (g == 0) rowst[n] = E;
}

__global__ void k_scatter(const int* __restrict__ ei, int* __restrict__ fill,
                          int* __restrict__ esrc, int E) {
    int e = blockIdx.x * 256 + threadIdx.x;
    if (e < E) {
        int s = ei[e];
        int d = ei[E + e];
        int pos = atomicAdd(&fill[d], 1);
        esrc[pos] = s;
    }
}

// ---------------- GEMM: C[M,64] = A[M,K] @ W[K,64]  (fp32, tiled) ----------------

__global__ __launch_bounds__(256) void gemm_n64(const float* __restrict__ A, int lda, int K, int M,
                                                const float* __restrict__ W, float* __restrict__ C) {
    __shared__ float as[16][68];   // [k][m], padded: row = 272B (16B-aligned), banks ok
    __shared__ float ws[16][64];   // [k][n]
    const int tid = threadIdx.x;
    const int row0 = blockIdx.x * 64;
    const int tr = tid >> 4;       // 0..15 -> 4 output rows each
    const int tc = tid & 15;       // 0..15 -> 4 output cols each
    const int lr = tid >> 2;       // 0..63 loader row
    const int lq = tid & 3;        // 0..3  loader k-quad

    float acc[4][4];
#pragma unroll
    for (int i = 0; i < 4; i++)
#pragma unroll
        for (int j = 0; j < 4; j++) acc[i][j] = 0.f;

    for (int k0 = 0; k0 < K; k0 += 16) {
        // stage A tile (64 rows x 16 k), transposed into as[k][m]
        int ar = row0 + lr;
        const float* Ap = A + (size_t)min(ar, M - 1) * lda + k0 + lq * 4;
        bool rok = (ar < M);
#pragma unroll
        for (int j = 0; j < 4; j++) {
            int kk = k0 + lq * 4 + j;
            float v = (rok && kk < K) ? Ap[j] : 0.f;
            as[lq * 4 + j][lr] = v;
        }
        // stage W tile (16 k x 64 n)
        {
            int idx = tid * 4;
            int kk = idx >> 6;
            int c = idx & 63;
            float4 w4 = make_float4(0.f, 0.f, 0.f, 0.f);
            if (k0 + kk < K) w4 = *(const float4*)&W[(size_t)(k0 + kk) * 64 + c];
            *(float4*)&ws[kk][c] = w4;
        }
        __syncthreads();
#pragma unroll
        for (int kk = 0; kk < 16; kk++) {
            float4 a4 = *(const float4*)&as[kk][tr * 4];
            float4 b4 = *(const float4*)&ws[kk][tc * 4];
            float a[4] = {a4.x, a4.y, a4.z, a4.w};
            float b[4] = {b4.x, b4.y, b4.z, b4.w};
#pragma unroll
            for (int i = 0; i < 4; i++)
#pragma unroll
                for (int j = 0; j < 4; j++) acc[i][j] += a[i] * b[j];
        }
        __syncthreads();
    }
#pragma unroll
    for (int i = 0; i < 4; i++) {
        int r = row0 + tr * 4 + i;
        if (r < M) {
            float4 o = make_float4(acc[i][0], acc[i][1], acc[i][2], acc[i][3]);
            *(float4*)&C[(size_t)r * 64 + tc * 4] = o;
        }
    }
}

// ---------------- GCN aggregate: wave per node, lane = channel ----------------
// O[i][c] = relu( dinv[i] * ( sum_{s in N(i)} H[s][c]*dinv[s] + H[i][c]*dinv[i] ) + b[c] )

__global__ __launch_bounds__(256) void gcn_prop(const float* __restrict__ H, float* __restrict__ O,
                                                const int* __restrict__ rowst,
                                                const int* __restrict__ esrc,
                                                const float* __restrict__ dinv,
                                                const float* __restrict__ bias, int n) {
    int i = blockIdx.x * 4 + (threadIdx.x >> 6);
    if (i >= n) return;
    int c = threadIdx.x & 63;
    float di = dinv[i];
    float acc = H[(size_t)i * 64 + c] * di;  // self-loop (×di again below)
    int j0 = rowst[i], j1 = rowst[i + 1];
    for (int j = j0; j < j1; j++) {
        int s = esrc[j];
        acc += H[(size_t)s * 64 + c] * dinv[s];
    }
    float v = acc * di + bias[c];
    O[(size_t)i * 64 + c] = fmaxf(v, 0.f);
}

// ---------------- GAT transform: hg = X@Wg [N,14]; a_src/a_dst [N,2] ----------------

__global__ __launch_bounds__(256) void gat_gemm(const float* __restrict__ X,
                                                const float* __restrict__ Wg,
                                                const float* __restrict__ att_src,
                                                const float* __restrict__ att_dst,
                                                float* __restrict__ HG,
                                                float* __restrict__ AS, float* __restrict__ AD,
                                                int n) {
    __shared__ float xs[64 * 65];
    __shared__ float wg[64 * C14];
    __shared__ float hgs[64 * 15];
    const int tid = threadIdx.x;
    const int n0 = blockIdx.x * 64;

    for (int i = tid; i < 64 * C14; i += 256) wg[i] = Wg[i];
    for (int i = tid * 4; i < 4096; i += 1024) {
        int nn = i >> 6, k = i & 63;
        int g = n0 + nn;
        float4 v = make_float4(0.f, 0.f, 0.f, 0.f);
        if (g < n) v = *(const float4*)&X[(size_t)g * 64 + k];
        xs[nn * 65 + k] = v.x;
        xs[nn * 65 + k + 1] = v.y;
        xs[nn * 65 + k + 2] = v.z;
        xs[nn * 65 + k + 3] = v.w;
    }
    __syncthreads();

    const int nn = tid & 63;      // node within tile (lane)
    const int q = tid >> 6;       // wave id -> col group
    float acc[4] = {0.f, 0.f, 0.f, 0.f};
    for (int k = 0; k < 64; k++) {
        float a = xs[nn * 65 + k];
#pragma unroll
        for (int j = 0; j < 4; j++) {
            int c = q + 4 * j;
            if (c < C14) acc[j] += a * wg[k * C14 + c];
        }
    }
    int g = n0 + nn;
#pragma unroll
    for (int j = 0; j < 4; j++) {
        int c = q + 4 * j;
        if (c < C14) {
            hgs[nn * 15 + c] = acc[j];
            if (g < n) HG[(size_t)g * C14 + c] = acc[j];
        }
    }
    __syncthreads();

    if (tid < 128) {
        int nloc = tid & 63;
        int h = tid >> 6;
        int gg = n0 + nloc;
        if (gg < n) {
            float s1 = 0.f, s2 = 0.f;
#pragma unroll
            for (int cc = 0; cc < 7; cc++) {
                float hv = hgs[nloc * 15 + h * 7 + cc];
                s1 += hv * att_src[h * 7 + cc];
                s2 += hv * att_dst[h * 7 + cc];
            }
            AS[(size_t)gg * 2 + h] = s1;
            AD[(size_t)gg * 2 + h] = s2;
        }
    }
}

// ---------------- GAT aggregate + bias + log_softmax: wave per node ----------------

__global__ __launch_bounds__(256) void gat_agg(const float* __restrict__ HG,
                                               const float* __restrict__ AS,
                                               const float* __restrict__ AD,
                                               const int* __restrict__ rowst,
                                               const int* __restrict__ esrc,
                                               const float* __restrict__ bg,
                                               float* __restrict__ out, int n) {
    int i = blockIdx.x * 4 + (threadIdx.x >> 6);
    if (i >= n) return;
    int c = threadIdx.x & 63;           // active channels: c < 14
    int h = (c < 7) ? 0 : 1;
    float adst_i = AD[(size_t)i * 2 + h];
    float asrc_i = AS[(size_t)i * 2 + h];
    auto lrelu = [](float x) { return x > 0.f ? x : 0.2f * x; };

    // pass 1: segment max (self-loop + in-edges)
    float m = lrelu(asrc_i + adst_i);
    int j0 = rowst[i], j1 = rowst[i + 1];
    for (int j = j0; j < j1; j++) {
        int s = esrc[j];
        float e = lrelu(AS[(size_t)s * 2 + h] + adst_i);
        m = fmaxf(m, e);
    }
    // pass 2: sum of p and weighted feature accumulate
    float p0 = __expf(lrelu(asrc_i + adst_i) - m);
    float ssum = p0;
    float hgv = 0.f;
    if (c < C14) hgv = HG[(size_t)i * C14 + c];
    float acc = hgv * p0;
    for (int j = j0; j < j1; j++) {
        int s = esrc[j];
        float e = lrelu(AS[(size_t)s * 2 + h] + adst_i);
        float pp = __expf(e - m);
        ssum += pp;
        float hv = 0.f;
        if (c < C14) hv = HG[(size_t)s * C14 + c];
        acc += hv * pp;
    }
    float v = acc / (ssum + 1e-16f) + ((c < C14) ? bg[c] : 0.f);

    // log_softmax across the 14 channels (within 16-lane group; lanes 14,15 neutral)
    float vv = (c < C14) ? v : -__builtin_inff();
    float maxv = vv;
#pragma unroll
    for (int d = 1; d < 16; d <<= 1) maxv = fmaxf(maxv, __shfl_xor(maxv, d, 16));
    float ee = (c < C14) ? __expf(v - maxv) : 0.f;
    float s2 = ee;
#pragma unroll
    for (int d = 1; d < 16; d <<= 1) s2 += __shfl_xor(s2, d, 16);
    if (c < C14) out[(size_t)i * C14 + c] = v - maxv - __logf(s2);
}

// ---------------- launch ----------------

extern "C" void kernel_launch(void* const* d_in, const int* in_sizes, int n_in,
                              void* d_out, int out_size, void* d_ws, size_t ws_size,
                              hipStream_t stream) {
    const float* x       = (const float*)d_in[0];
    const int*   ei      = (const int*)d_in[1];
    const float* W1      = (const float*)d_in[2];
    const float* b1      = (const float*)d_in[3];
    const float* W2      = (const float*)d_in[4];
    const float* b2      = (const float*)d_in[5];
    const float* Wg      = (const float*)d_in[6];
    const float* att_src = (const float*)d_in[7];
    const float* att_dst = (const float*)d_in[8];
    const float* bg      = (const float*)d_in[9];

    const int N = in_sizes[0] / F_IN;
    const int E = in_sizes[1] / 2;

    char* p = (char*)d_ws;
    auto alloc = [&](size_t bytes) {
        char* r = p;
        p += (bytes + 255) & ~(size_t)255;
        return r;
    };
    float* h    = (float*)alloc((size_t)N * 64 * 4);
    float* g    = (float*)alloc((size_t)N * 64 * 4);
    float* hg   = (float*)alloc((size_t)N * C14 * 4);
    float* As   = (float*)alloc((size_t)N * 2 * 4);
    float* Ad   = (float*)alloc((size_t)N * 2 * 4);
    float* dinv = (float*)alloc((size_t)N * 4);
    int* cnt    = (int*)alloc((size_t)N * 4);
    int* rowst  = (int*)alloc((size_t)(N + 1) * 4);
    int* fill   = (int*)alloc((size_t)N * 4);
    int* esrc   = (int*)alloc((size_t)E * 4);
    int* bsum   = (int*)alloc(128 * 4);
    int* boff   = (int*)alloc(128 * 4);

    const int gN = (N + 255) / 256;
    const int gE = (E + 255) / 256;
    const int nb = (N + 1023) / 1024;     // 98 <= 128
    const int gW = (N + 3) / 4;           // wave-per-node kernels
    const int gT = (N + 63) / 64;         // 64-row GEMM tiles

    // CSR by dst (real edges only; self-loops handled analytically)
    k_zero_int<<<gN, 256, 0, stream>>>(cnt, N);
    k_hist<<<gE, 256, 0, stream>>>(ei + E, cnt, E);
    k_dinv<<<gN, 256, 0, stream>>>(cnt, dinv, N);
    k_scan1<<<nb, 1024, 0, stream>>>(cnt, rowst, bsum, N);
    k_scan2<<<1, 128, 0, stream>>>(bsum, boff, nb);
    k_scan3<<<nb, 1024, 0, stream>>>(rowst, boff, fill, N, E);
    k_scatter<<<gE, 256, 0, stream>>>(ei, fill, esrc, E);

    // GCN layer 1
    gemm_n64<<<gT, 256, 0, stream>>>(x, F_IN, F_IN, N, W1, h);
    gcn_prop<<<gW, 256, 0, stream>>>(h, g, rowst, esrc, dinv, b1, N);
    // GCN layer 2
    gemm_n64<<<gT, 256, 0, stream>>>(g, 64, 64, N, W2, h);
    gcn_prop<<<gW, 256, 0, stream>>>(h, g, rowst, esrc, dinv, b2, N);
    // GAT + log_softmax
    gat_gemm<<<gT, 256, 0, stream>>>(g, Wg, att_src, att_dst, hg, As, Ad, N);
    gat_agg<<<gW, 256, 0, stream>>>(hg, As, Ad, rowst, esrc, bg, (float*)d_out, N);
}

// Round 2
// 1396.146 us; speedup vs baseline: 1.3434x; 1.3434x over previous
//
#include <hip/hip_runtime.h>
#include <hip/hip_bf16.h>

#define F_IN 1433
#define HID  64
#define C14  14

typedef __attribute__((ext_vector_type(8))) short short8;
typedef __attribute__((ext_vector_type(4))) float float4v;

__device__ inline short f2bf(float f) {
    union { float f; unsigned u; } c; c.f = f;
    unsigned u = c.u;
    u += 0x7fffu + ((u >> 16) & 1u);   // RNE
    return (short)(u >> 16);
}

// ---------------- CSR build ----------------

__global__ void k_zero_int(int* __restrict__ p, int n) {
    int i = blockIdx.x * 256 + threadIdx.x;
    if (i < n) p[i] = 0;
}

__global__ void k_hist(const int* __restrict__ dst, int* __restrict__ cnt, int E) {
    int e = blockIdx.x * 256 + threadIdx.x;
    if (e < E) atomicAdd(&cnt[dst[e]], 1);
}

__global__ void k_dinv(const int* __restrict__ cnt, float* __restrict__ dinv, int n) {
    int i = blockIdx.x * 256 + threadIdx.x;
    if (i < n) dinv[i] = rsqrtf((float)cnt[i] + 1.0f);  // +1 self-loop
}

__global__ __launch_bounds__(1024) void k_scan1(const int* __restrict__ cnt,
                                                int* __restrict__ excl,
                                                int* __restrict__ bsum, int n) {
    __shared__ int sd[1024];
    int tid = threadIdx.x;
    int g = blockIdx.x * 1024 + tid;
    int v = (g < n) ? cnt[g] : 0;
    sd[tid] = v;
    __syncthreads();
    for (int off = 1; off < 1024; off <<= 1) {
        int t = (tid >= off) ? sd[tid - off] : 0;
        __syncthreads();
        sd[tid] += t;
        __syncthreads();
    }
    if (g < n) excl[g] = sd[tid] - v;
    if (tid == 1023) bsum[blockIdx.x] = sd[1023];
}

__global__ __launch_bounds__(128) void k_scan2(const int* __restrict__ bsum,
                                               int* __restrict__ boff, int nb) {
    __shared__ int sd[128];
    int tid = threadIdx.x;
    int v = (tid < nb) ? bsum[tid] : 0;
    sd[tid] = v;
    __syncthreads();
    for (int off = 1; off < 128; off <<= 1) {
        int t = (tid >= off) ? sd[tid - off] : 0;
        __syncthreads();
        sd[tid] += t;
        __syncthreads();
    }
    if (tid < nb) boff[tid] = sd[tid] - v;
}

__global__ __launch_bounds__(1024) void k_scan3(int* __restrict__ rowst,
                                                const int* __restrict__ boff,
                                                int* __restrict__ fill, int n, int E) {
    int tid = threadIdx.x;
    int g = blockIdx.x * 1024 + tid;
    if (g < n) {
        int v = rowst[g] + boff[blockIdx.x];
        rowst[g] = v;
        fill[g] = v;
    }
    if (g == 0) rowst[n] = E;
}

__global__ void k_scatter(const int* __restrict__ ei, int* __restrict__ fill,
                          int* __restrict__ esrc, int E) {
    int e = blockIdx.x * 256 + threadIdx.x;
    if (e < E) {
        int s = ei[e];
        int d = ei[E + e];
        int pos = atomicAdd(&fill[d], 1);
        esrc[pos] = s;
    }
}

// ---------------- W transpose+cast: Wt[n][k] bf16, k padded to ldw ----------------

__global__ void k_prep_wt(const float* __restrict__ W, short* __restrict__ Wt,
                          int K, int ldw) {
    int n = blockIdx.y;
    int k = blockIdx.x * 256 + threadIdx.x;
    if (k < ldw) {
        float v = (k < K) ? W[(size_t)k * 64 + n] : 0.f;
        Wt[(size_t)n * ldw + k] = f2bf(v);
    }
}

// ---------------- MFMA GEMM: C[M,64] = A[M,K](fp32) @ W[K,64], via bf16 ----------------
// Block: 256 thr = 4 waves; tile 64 rows. Wave w: rows 16w..16w+15, 4 col-tiles of 16.
// A staged in LDS (bf16, stride 40 shorts); B-frags read direct from Wt (L2-hot).

__global__ __launch_bounds__(256) void gemm_mfma(const float* __restrict__ A, int K, int M,
                                                 const short* __restrict__ Wt, int ldw,
                                                 float* __restrict__ C) {
    __shared__ short As[64 * 40];
    const int tid = threadIdx.x;
    const int w = tid >> 6, l = tid & 63;
    const int row0 = blockIdx.x * 64;
    const int m16 = l & 15, q = l >> 4;      // frag row-within-tile, k-quad

    float4v acc[4];
#pragma unroll
    for (int t = 0; t < 4; t++) acc[t] = (float4v){0.f, 0.f, 0.f, 0.f};

    const int sr = tid >> 2;                 // staging row 0..63
    const int skq = (tid & 3) * 8;           // staging k-quad base
    const int ar = min(row0 + sr, M - 1);
    const float* Arow = A + (size_t)ar * K;

    const int nk = (K + 31) / 32;
    for (int ks = 0; ks < nk; ks++) {
        const int k0 = ks * 32;
        short tmp[8];
#pragma unroll
        for (int j = 0; j < 8; j++) {
            int kk = k0 + skq + j;
            float v = (kk < K) ? Arow[kk] : 0.f;
            tmp[j] = f2bf(v);
        }
        *(short8*)&As[sr * 40 + skq] = *(const short8*)tmp;   // 16B aligned
        __syncthreads();

        short8 afrag = *(const short8*)&As[(16 * w + m16) * 40 + q * 8];
#pragma unroll
        for (int t = 0; t < 4; t++) {
            short8 bfrag = *(const short8*)&Wt[(size_t)(16 * t + m16) * ldw + k0 + q * 8];
            acc[t] = __builtin_amdgcn_mfma_f32_16x16x32_bf16(afrag, bfrag, acc[t], 0, 0, 0);
        }
        __syncthreads();
    }

    // C/D layout: col = lane&15, row = (lane>>4)*4 + i
#pragma unroll
    for (int t = 0; t < 4; t++) {
#pragma unroll
        for (int i = 0; i < 4; i++) {
            int rr = row0 + 16 * w + q * 4 + i;
            if (rr < M) C[(size_t)rr * 64 + 16 * t + m16] = acc[t][i];
        }
    }
}

// ---------------- GCN aggregate: wave per node, lane = channel ----------------

__global__ __launch_bounds__(256) void gcn_prop(const float* __restrict__ H, float* __restrict__ O,
                                                const int* __restrict__ rowst,
                                                const int* __restrict__ esrc,
                                                const float* __restrict__ dinv,
                                                const float* __restrict__ bias, int n) {
    int i = blockIdx.x * 4 + (threadIdx.x >> 6);
    if (i >= n) return;
    int c = threadIdx.x & 63;
    float di = dinv[i];
    float acc = H[(size_t)i * 64 + c] * di;
    int j0 = rowst[i], j1 = rowst[i + 1];
    int j = j0;
    for (; j + 4 <= j1; j += 4) {
        int s0 = esrc[j], s1 = esrc[j + 1], s2 = esrc[j + 2], s3 = esrc[j + 3];
        float d0 = dinv[s0], d1 = dinv[s1], d2 = dinv[s2], d3 = dinv[s3];
        float h0 = H[(size_t)s0 * 64 + c], h1 = H[(size_t)s1 * 64 + c];
        float h2 = H[(size_t)s2 * 64 + c], h3 = H[(size_t)s3 * 64 + c];
        acc += h0 * d0 + h1 * d1 + h2 * d2 + h3 * d3;
    }
    for (; j < j1; j++) {
        int s = esrc[j];
        acc += H[(size_t)s * 64 + c] * dinv[s];
    }
    float v = acc * di + bias[c];
    O[(size_t)i * 64 + c] = fmaxf(v, 0.f);
}

// ---------------- GAT transform ----------------

__global__ __launch_bounds__(256) void gat_gemm(const float* __restrict__ X,
                                                const float* __restrict__ Wg,
                                                const float* __restrict__ att_src,
                                                const float* __restrict__ att_dst,
                                                float* __restrict__ HG,
                                                float* __restrict__ AS, float* __restrict__ AD,
                                                int n) {
    __shared__ float xs[64 * 65];
    __shared__ float wg[64 * C14];
    __shared__ float hgs[64 * 15];
    const int tid = threadIdx.x;
    const int n0 = blockIdx.x * 64;

    for (int i = tid; i < 64 * C14; i += 256) wg[i] = Wg[i];
    for (int i = tid * 4; i < 4096; i += 1024) {
        int nn = i >> 6, k = i & 63;
        int g = n0 + nn;
        float4 v = make_float4(0.f, 0.f, 0.f, 0.f);
        if (g < n) v = *(const float4*)&X[(size_t)g * 64 + k];
        xs[nn * 65 + k] = v.x;
        xs[nn * 65 + k + 1] = v.y;
        xs[nn * 65 + k + 2] = v.z;
        xs[nn * 65 + k + 3] = v.w;
    }
    __syncthreads();

    const int nn = tid & 63;
    const int qq = tid >> 6;
    float acc[4] = {0.f, 0.f, 0.f, 0.f};
    for (int k = 0; k < 64; k++) {
        float a = xs[nn * 65 + k];
#pragma unroll
        for (int j = 0; j < 4; j++) {
            int c = qq + 4 * j;
            if (c < C14) acc[j] += a * wg[k * C14 + c];
        }
    }
    int g = n0 + nn;
#pragma unroll
    for (int j = 0; j < 4; j++) {
        int c = qq + 4 * j;
        if (c < C14) {
            hgs[nn * 15 + c] = acc[j];
            if (g < n) HG[(size_t)g * C14 + c] = acc[j];
        }
    }
    __syncthreads();

    if (tid < 128) {
        int nloc = tid & 63;
        int h = tid >> 6;
        int gg = n0 + nloc;
        if (gg < n) {
            float s1 = 0.f, s2 = 0.f;
#pragma unroll
            for (int cc = 0; cc < 7; cc++) {
                float hv = hgs[nloc * 15 + h * 7 + cc];
                s1 += hv * att_src[h * 7 + cc];
                s2 += hv * att_dst[h * 7 + cc];
            }
            AS[(size_t)gg * 2 + h] = s1;
            AD[(size_t)gg * 2 + h] = s2;
        }
    }
}

// ---------------- GAT aggregate + log_softmax: 16 lanes per node, online softmax ----------------

__global__ __launch_bounds__(256) void gat_agg(const float* __restrict__ HG,
                                               const float* __restrict__ AS,
                                               const float* __restrict__ AD,
                                               const int* __restrict__ rowst,
                                               const int* __restrict__ esrc,
                                               const float* __restrict__ bg,
                                               float* __restrict__ out, int n) {
    int i = blockIdx.x * 16 + (threadIdx.x >> 4);
    if (i >= n) return;
    int c = threadIdx.x & 15;
    int h = (c < 7) ? 0 : 1;
    float adst = AD[(size_t)i * 2 + h];
    float asrc = AS[(size_t)i * 2 + h];
    auto lrelu = [](float x) { return x > 0.f ? x : 0.2f * x; };

    // online softmax state (self-loop initializes)
    float m = lrelu(asrc + adst);
    float ssum = 1.f;
    float acc = (c < C14) ? HG[(size_t)i * C14 + c] : 0.f;

    int j0 = rowst[i], j1 = rowst[i + 1];
    int j = j0;
    for (; j + 4 <= j1; j += 4) {
        int s0 = esrc[j], s1 = esrc[j + 1], s2 = esrc[j + 2], s3 = esrc[j + 3];
        float e0 = lrelu(AS[(size_t)s0 * 2 + h] + adst);
        float e1 = lrelu(AS[(size_t)s1 * 2 + h] + adst);
        float e2 = lrelu(AS[(size_t)s2 * 2 + h] + adst);
        float e3 = lrelu(AS[(size_t)s3 * 2 + h] + adst);
        float g0 = (c < C14) ? HG[(size_t)s0 * C14 + c] : 0.f;
        float g1 = (c < C14) ? HG[(size_t)s1 * C14 + c] : 0.f;
        float g2 = (c < C14) ? HG[(size_t)s2 * C14 + c] : 0.f;
        float g3 = (c < C14) ? HG[(size_t)s3 * C14 + c] : 0.f;
#pragma unroll
        for (int u = 0; u < 4; u++) {
            float e = (u == 0) ? e0 : (u == 1) ? e1 : (u == 2) ? e2 : e3;
            float gv = (u == 0) ? g0 : (u == 1) ? g1 : (u == 2) ? g2 : g3;
            float nm = fmaxf(m, e);
            float sc = __expf(m - nm);
            float pe = __expf(e - nm);
            ssum = ssum * sc + pe;
            acc = acc * sc + gv * pe;
            m = nm;
        }
    }
    for (; j < j1; j++) {
        int s = esrc[j];
        float e = lrelu(AS[(size_t)s * 2 + h] + adst);
        float gv = (c < C14) ? HG[(size_t)s * C14 + c] : 0.f;
        float nm = fmaxf(m, e);
        float sc = __expf(m - nm);
        float pe = __expf(e - nm);
        ssum = ssum * sc + pe;
        acc = acc * sc + gv * pe;
        m = nm;
    }

    float v = acc / ssum + ((c < C14) ? bg[c] : 0.f);

    // log_softmax across 14 channels within the 16-lane group
    float vv = (c < C14) ? v : -__builtin_inff();
    float maxv = vv;
#pragma unroll
    for (int d = 1; d < 16; d <<= 1) maxv = fmaxf(maxv, __shfl_xor(maxv, d, 16));
    float ee = (c < C14) ? __expf(v - maxv) : 0.f;
    float s2 = ee;
#pragma unroll
    for (int d = 1; d < 16; d <<= 1) s2 += __shfl_xor(s2, d, 16);
    if (c < C14) out[(size_t)i * C14 + c] = v - maxv - __logf(s2);
}

// ---------------- launch ----------------

extern "C" void kernel_launch(void* const* d_in, const int* in_sizes, int n_in,
                              void* d_out, int out_size, void* d_ws, size_t ws_size,
                              hipStream_t stream) {
    const float* x       = (const float*)d_in[0];
    const int*   ei      = (const int*)d_in[1];
    const float* W1      = (const float*)d_in[2];
    const float* b1      = (const float*)d_in[3];
    const float* W2      = (const float*)d_in[4];
    const float* b2      = (const float*)d_in[5];
    const float* Wg      = (const float*)d_in[6];
    const float* att_src = (const float*)d_in[7];
    const float* att_dst = (const float*)d_in[8];
    const float* bg      = (const float*)d_in[9];

    const int N = in_sizes[0] / F_IN;
    const int E = in_sizes[1] / 2;
    const int K1P = 1440;   // 45 * 32

    char* p = (char*)d_ws;
    auto alloc = [&](size_t bytes) {
        char* r = p;
        p += (bytes + 255) & ~(size_t)255;
        return r;
    };
    float* h    = (float*)alloc((size_t)N * 64 * 4);
    float* g    = (float*)alloc((size_t)N * 64 * 4);
    float* hg   = (float*)alloc((size_t)N * C14 * 4);
    float* As   = (float*)alloc((size_t)N * 2 * 4);
    float* Ad   = (float*)alloc((size_t)N * 2 * 4);
    float* dinv = (float*)alloc((size_t)N * 4);
    int* cnt    = (int*)alloc((size_t)N * 4);
    int* rowst  = (int*)alloc((size_t)(N + 1) * 4);
    int* fill   = (int*)alloc((size_t)N * 4);
    int* esrc   = (int*)alloc((size_t)E * 4);
    int* bsum   = (int*)alloc(128 * 4);
    int* boff   = (int*)alloc(128 * 4);
    short* Wt1  = (short*)alloc((size_t)64 * K1P * 2);
    short* Wt2  = (short*)alloc((size_t)64 * 64 * 2);

    const int gN = (N + 255) / 256;
    const int gE = (E + 255) / 256;
    const int nb = (N + 1023) / 1024;
    const int gW = (N + 3) / 4;
    const int gA = (N + 15) / 16;
    const int gT = (N + 63) / 64;

    // weight prep (independent of CSR)
    k_prep_wt<<<dim3((K1P + 255) / 256, 64), 256, 0, stream>>>(W1, Wt1, F_IN, K1P);
    k_prep_wt<<<dim3(1, 64), 256, 0, stream>>>(W2, Wt2, 64, 64);

    // CSR by dst (real edges only; self-loops analytic)
    k_zero_int<<<gN, 256, 0, stream>>>(cnt, N);
    k_hist<<<gE, 256, 0, stream>>>(ei + E, cnt, E);
    k_dinv<<<gN, 256, 0, stream>>>(cnt, dinv, N);
    k_scan1<<<nb, 1024, 0, stream>>>(cnt, rowst, bsum, N);
    k_scan2<<<1, 128, 0, stream>>>(bsum, boff, nb);
    k_scan3<<<nb, 1024, 0, stream>>>(rowst, boff, fill, N, E);
    k_scatter<<<gE, 256, 0, stream>>>(ei, fill, esrc, E);

    // GCN layer 1
    gemm_mfma<<<gT, 256, 0, stream>>>(x, F_IN, N, Wt1, K1P, h);
    gcn_prop<<<gW, 256, 0, stream>>>(h, g, rowst, esrc, dinv, b1, N);
    // GCN layer 2
    gemm_mfma<<<gT, 256, 0, stream>>>(g, 64, N, Wt2, 64, h);
    gcn_prop<<<gW, 256, 0, stream>>>(h, g, rowst, esrc, dinv, b2, N);
    // GAT + log_softmax
    gat_gemm<<<gT, 256, 0, stream>>>(g, Wg, att_src, att_dst, hg, As, Ad, N);
    gat_agg<<<gA, 256, 0, stream>>>(hg, As, Ad, rowst, esrc, bg, (float*)d_out, N);
}

// Round 3
// 1238.681 us; speedup vs baseline: 1.5141x; 1.1271x over previous
//
#include <hip/hip_runtime.h>
#include <hip/hip_bf16.h>

#define F_IN 1433
#define HID  64
#define C14  14

typedef __attribute__((ext_vector_type(8))) short short8;
typedef __attribute__((ext_vector_type(4))) float float4v;

__device__ inline short f2bf(float f) {
    union { float f; unsigned u; } c; c.f = f;
    unsigned u = c.u;
    u += 0x7fffu + ((u >> 16) & 1u);   // RNE
    return (short)(u >> 16);
}

// ---------------- CSR build ----------------

__global__ void k_zero_int(int* __restrict__ p, int n) {
    int i = blockIdx.x * 256 + threadIdx.x;
    if (i < n) p[i] = 0;
}

__global__ void k_hist(const int* __restrict__ dst, int* __restrict__ cnt, int E) {
    int e = blockIdx.x * 256 + threadIdx.x;
    if (e < E) atomicAdd(&cnt[dst[e]], 1);
}

__global__ void k_dinv(const int* __restrict__ cnt, float* __restrict__ dinv, int n) {
    int i = blockIdx.x * 256 + threadIdx.x;
    if (i < n) dinv[i] = rsqrtf((float)cnt[i] + 1.0f);  // +1 self-loop
}

__global__ __launch_bounds__(1024) void k_scan1(const int* __restrict__ cnt,
                                                int* __restrict__ excl,
                                                int* __restrict__ bsum, int n) {
    __shared__ int sd[1024];
    int tid = threadIdx.x;
    int g = blockIdx.x * 1024 + tid;
    int v = (g < n) ? cnt[g] : 0;
    sd[tid] = v;
    __syncthreads();
    for (int off = 1; off < 1024; off <<= 1) {
        int t = (tid >= off) ? sd[tid - off] : 0;
        __syncthreads();
        sd[tid] += t;
        __syncthreads();
    }
    if (g < n) excl[g] = sd[tid] - v;
    if (tid == 1023) bsum[blockIdx.x] = sd[1023];
}

__global__ __launch_bounds__(128) void k_scan2(const int* __restrict__ bsum,
                                               int* __restrict__ boff, int nb) {
    __shared__ int sd[128];
    int tid = threadIdx.x;
    int v = (tid < nb) ? bsum[tid] : 0;
    sd[tid] = v;
    __syncthreads();
    for (int off = 1; off < 128; off <<= 1) {
        int t = (tid >= off) ? sd[tid - off] : 0;
        __syncthreads();
        sd[tid] += t;
        __syncthreads();
    }
    if (tid < nb) boff[tid] = sd[tid] - v;
}

__global__ __launch_bounds__(1024) void k_scan3(int* __restrict__ rowst,
                                                const int* __restrict__ boff,
                                                int* __restrict__ fill, int n, int E) {
    int tid = threadIdx.x;
    int g = blockIdx.x * 1024 + tid;
    if (g < n) {
        int v = rowst[g] + boff[blockIdx.x];
        rowst[g] = v;
        fill[g] = v;
    }
    if (g == 0) rowst[n] = E;
}

__global__ void k_scatter(const int* __restrict__ ei, int* __restrict__ fill,
                          int* __restrict__ esrc, int E) {
    int e = blockIdx.x * 256 + threadIdx.x;
    if (e < E) {
        int s = ei[e];
        int d = ei[E + e];
        int pos = atomicAdd(&fill[d], 1);
        esrc[pos] = s;
    }
}

// ---------------- B prep: fragment-ordered bf16 ----------------
// Bf[((ks*4 + t)*2 + s)*64 + l][j] = bf16( W[ks*64 + s*32 + (l>>4)*8 + j][t*16 + (l&15)] )

__global__ void k_prep_bf(const float* __restrict__ W, short* __restrict__ Bf,
                          int K, int nchunk) {
    int id = blockIdx.x * 256 + threadIdx.x;
    int total = nchunk * 512;
    if (id >= total) return;
    int l = id & 63;
    int s = (id >> 6) & 1;
    int t = (id >> 7) & 3;
    int ks = id >> 9;
    int n = t * 16 + (l & 15);
    int k0 = ks * 64 + s * 32 + (l >> 4) * 8;
    short tmp[8];
#pragma unroll
    for (int j = 0; j < 8; j++) {
        int k = k0 + j;
        tmp[j] = (k < K) ? f2bf(W[(size_t)k * 64 + n]) : (short)0;
    }
    *(short8*)&Bf[(size_t)id * 8] = *(const short8*)tmp;
}

// ---------------- MFMA GEMM: C[M,64] = (A[M,K] @ W[K,64]) * dinv[row] ----------------
// 128-row tile, 64-K chunks, register double-buffer, XOR-swizzled A LDS,
// frag-ordered B staged to LDS. 4 waves: wave w rows 32w..32w+31.

__global__ __launch_bounds__(256) void gemm_mfma(const float* __restrict__ A, int K, int nchunk,
                                                 int M, const short* __restrict__ Bf,
                                                 const float* __restrict__ dinv,
                                                 float* __restrict__ C) {
    __shared__ short As[128 * 64];   // [row][k-chunk], 16B blocks XOR-swizzled by row&7
    __shared__ short Bs[4096];       // frag-ordered chunk copy
    const int tid = threadIdx.x;
    const int w = tid >> 6, l = tid & 63;
    const int row0 = blockIdx.x * 128;
    const int m16 = l & 15, q = l >> 4;
    const int sr = tid >> 1, half = tid & 1;          // staging: row, k-half
    const int ar = min(row0 + sr, M - 1);
    const float* __restrict__ Arow = A + (size_t)ar * K;

    float4v acc[2][4];
#pragma unroll
    for (int mi = 0; mi < 2; mi++)
#pragma unroll
        for (int t = 0; t < 4; t++) acc[mi][t] = (float4v){0.f, 0.f, 0.f, 0.f};

    float pre[32];
    int4 preB0, preB1;

    auto issue = [&](int ks) {
        const float* Ap = Arow + ks * 64 + half * 32;
        if (ks * 64 + 64 <= K) {
#pragma unroll
            for (int j = 0; j < 32; j++) pre[j] = Ap[j];
        } else {
#pragma unroll
            for (int j = 0; j < 32; j++) {
                int kk = ks * 64 + half * 32 + j;
                pre[j] = (kk < K) ? Ap[j] : 0.f;
            }
        }
        const short* bsrc = Bf + (size_t)ks * 4096;
        preB0 = *(const int4*)&bsrc[tid * 16];
        preB1 = *(const int4*)&bsrc[tid * 16 + 8];
    };

    auto stage = [&]() {
#pragma unroll
        for (int g4 = 0; g4 < 4; g4++) {
            short t8[8];
#pragma unroll
            for (int j = 0; j < 8; j++) t8[j] = f2bf(pre[g4 * 8 + j]);
            int p = half * 4 + g4;
            int pp = p ^ (sr & 7);
            *(short8*)&As[sr * 64 + pp * 8] = *(const short8*)t8;
        }
        *(int4*)&Bs[tid * 16] = preB0;
        *(int4*)&Bs[tid * 16 + 8] = preB1;
    };

    auto compute = [&]() {
#pragma unroll
        for (int s = 0; s < 2; s++) {
            short8 a[2];
#pragma unroll
            for (int mi = 0; mi < 2; mi++) {
                int row = w * 32 + mi * 16 + m16;
                int p = s * 4 + q;
                a[mi] = *(const short8*)&As[row * 64 + (p ^ (row & 7)) * 8];
            }
#pragma unroll
            for (int t = 0; t < 4; t++) {
                short8 b = *(const short8*)&Bs[(t * 2 + s) * 512 + l * 8];
                acc[0][t] = __builtin_amdgcn_mfma_f32_16x16x32_bf16(a[0], b, acc[0][t], 0, 0, 0);
                acc[1][t] = __builtin_amdgcn_mfma_f32_16x16x32_bf16(a[1], b, acc[1][t], 0, 0, 0);
            }
        }
    };

    issue(0);
    stage();
    __syncthreads();
    for (int ks = 0; ks < nchunk; ks++) {
        bool more = (ks + 1 < nchunk);
        if (more) issue(ks + 1);
        compute();
        __syncthreads();
        if (more) {
            stage();
            __syncthreads();
        }
    }

    // C/D layout: col = t*16 + (lane&15), row = (lane>>4)*4 + i
#pragma unroll
    for (int mi = 0; mi < 2; mi++) {
#pragma unroll
        for (int i = 0; i < 4; i++) {
            int rr = row0 + w * 32 + mi * 16 + q * 4 + i;
            if (rr < M) {
                float dv = dinv ? dinv[rr] : 1.f;
#pragma unroll
                for (int t = 0; t < 4; t++)
                    C[(size_t)rr * 64 + t * 16 + m16] = acc[mi][t][i] * dv;
            }
        }
    }
}

// ---------------- GCN aggregate: 16 lanes/node, float4/lane ----------------
// H is pre-scaled by dinv[row] in the gemm epilogue.
// O[i][c] = relu( dinv[i] * ( H[i][c] + sum_{s in N(i)} H[s][c] ) + b[c] )

__global__ __launch_bounds__(256) void gcn_prop(const float* __restrict__ H, float* __restrict__ O,
                                                const int* __restrict__ rowst,
                                                const int* __restrict__ esrc,
                                                const float* __restrict__ dinv,
                                                const float* __restrict__ bias, int n) {
    int i = blockIdx.x * 16 + (threadIdx.x >> 4);
    if (i >= n) return;
    int c0 = (threadIdx.x & 15) * 4;
    float4 acc = *(const float4*)&H[(size_t)i * 64 + c0];
    int j0 = rowst[i], j1 = rowst[i + 1];
    int j = j0;
    for (; j + 4 <= j1; j += 4) {
        int s0 = esrc[j], s1 = esrc[j + 1], s2 = esrc[j + 2], s3 = esrc[j + 3];
        float4 h0 = *(const float4*)&H[(size_t)s0 * 64 + c0];
        float4 h1 = *(const float4*)&H[(size_t)s1 * 64 + c0];
        float4 h2 = *(const float4*)&H[(size_t)s2 * 64 + c0];
        float4 h3 = *(const float4*)&H[(size_t)s3 * 64 + c0];
        acc.x += h0.x + h1.x + h2.x + h3.x;
        acc.y += h0.y + h1.y + h2.y + h3.y;
        acc.z += h0.z + h1.z + h2.z + h3.z;
        acc.w += h0.w + h1.w + h2.w + h3.w;
    }
    for (; j < j1; j++) {
        int s = esrc[j];
        float4 hv = *(const float4*)&H[(size_t)s * 64 + c0];
        acc.x += hv.x; acc.y += hv.y; acc.z += hv.z; acc.w += hv.w;
    }
    float di = dinv[i];
    float4 b4 = *(const float4*)&bias[c0];
    float4 o;
    o.x = fmaxf(acc.x * di + b4.x, 0.f);
    o.y = fmaxf(acc.y * di + b4.y, 0.f);
    o.z = fmaxf(acc.z * di + b4.z, 0.f);
    o.w = fmaxf(acc.w * di + b4.w, 0.f);
    *(float4*)&O[(size_t)i * 64 + c0] = o;
}

// ---------------- GAT transform: HG stride 16 ----------------

__global__ __launch_bounds__(256) void gat_gemm(const float* __restrict__ X,
                                                const float* __restrict__ Wg,
                                                const float* __restrict__ att_src,
                                                const float* __restrict__ att_dst,
                                                float* __restrict__ HG,
                                                float* __restrict__ AS, float* __restrict__ AD,
                                                int n) {
    __shared__ float xs[64 * 65];
    __shared__ float wg[64 * C14];
    __shared__ float hgs[64 * 15];
    const int tid = threadIdx.x;
    const int n0 = blockIdx.x * 64;

    for (int i = tid; i < 64 * C14; i += 256) wg[i] = Wg[i];
    for (int i = tid * 4; i < 4096; i += 1024) {
        int nn = i >> 6, k = i & 63;
        int g = n0 + nn;
        float4 v = make_float4(0.f, 0.f, 0.f, 0.f);
        if (g < n) v = *(const float4*)&X[(size_t)g * 64 + k];
        xs[nn * 65 + k] = v.x;
        xs[nn * 65 + k + 1] = v.y;
        xs[nn * 65 + k + 2] = v.z;
        xs[nn * 65 + k + 3] = v.w;
    }
    __syncthreads();

    const int nn = tid & 63;
    const int qq = tid >> 6;
    float acc[4] = {0.f, 0.f, 0.f, 0.f};
    for (int k = 0; k < 64; k++) {
        float a = xs[nn * 65 + k];
#pragma unroll
        for (int j = 0; j < 4; j++) {
            int c = qq + 4 * j;
            if (c < C14) acc[j] += a * wg[k * C14 + c];
        }
    }
    int g = n0 + nn;
#pragma unroll
    for (int j = 0; j < 4; j++) {
        int c = qq + 4 * j;
        if (c < C14) {
            hgs[nn * 15 + c] = acc[j];
            if (g < n) HG[(size_t)g * 16 + c] = acc[j];
        }
    }
    __syncthreads();

    if (tid < 128) {
        int nloc = tid & 63;
        int h = tid >> 6;
        int gg = n0 + nloc;
        if (gg < n) {
            float s1 = 0.f, s2 = 0.f;
#pragma unroll
            for (int cc = 0; cc < 7; cc++) {
                float hv = hgs[nloc * 15 + h * 7 + cc];
                s1 += hv * att_src[h * 7 + cc];
                s2 += hv * att_dst[h * 7 + cc];
            }
            AS[(size_t)gg * 2 + h] = s1;
            AD[(size_t)gg * 2 + h] = s2;
        }
    }
}

// ---------------- GAT aggregate + log_softmax: 16 lanes per node ----------------

__global__ __launch_bounds__(256) void gat_agg(const float* __restrict__ HG,
                                               const float* __restrict__ AS,
                                               const float* __restrict__ AD,
                                               const int* __restrict__ rowst,
                                               const int* __restrict__ esrc,
                                               const float* __restrict__ bg,
                                               float* __restrict__ out, int n) {
    int i = blockIdx.x * 16 + (threadIdx.x >> 4);
    if (i >= n) return;
    int c = threadIdx.x & 15;
    int h = (c < 7) ? 0 : 1;
    float adst = AD[(size_t)i * 2 + h];
    float asrc = AS[(size_t)i * 2 + h];
    auto lrelu = [](float x) { return x > 0.f ? x : 0.2f * x; };

    float m = lrelu(asrc + adst);
    float ssum = 1.f;
    float acc = (c < C14) ? HG[(size_t)i * 16 + c] : 0.f;

    int j0 = rowst[i], j1 = rowst[i + 1];
    int j = j0;
    for (; j + 4 <= j1; j += 4) {
        int s0 = esrc[j], s1 = esrc[j + 1], s2 = esrc[j + 2], s3 = esrc[j + 3];
        float e0 = lrelu(AS[(size_t)s0 * 2 + h] + adst);
        float e1 = lrelu(AS[(size_t)s1 * 2 + h] + adst);
        float e2 = lrelu(AS[(size_t)s2 * 2 + h] + adst);
        float e3 = lrelu(AS[(size_t)s3 * 2 + h] + adst);
        float g0 = (c < C14) ? HG[(size_t)s0 * 16 + c] : 0.f;
        float g1 = (c < C14) ? HG[(size_t)s1 * 16 + c] : 0.f;
        float g2 = (c < C14) ? HG[(size_t)s2 * 16 + c] : 0.f;
        float g3 = (c < C14) ? HG[(size_t)s3 * 16 + c] : 0.f;
#pragma unroll
        for (int u = 0; u < 4; u++) {
            float e = (u == 0) ? e0 : (u == 1) ? e1 : (u == 2) ? e2 : e3;
            float gv = (u == 0) ? g0 : (u == 1) ? g1 : (u == 2) ? g2 : g3;
            float nm = fmaxf(m, e);
            float sc = __expf(m - nm);
            float pe = __expf(e - nm);
            ssum = ssum * sc + pe;
            acc = acc * sc + gv * pe;
            m = nm;
        }
    }
    for (; j < j1; j++) {
        int s = esrc[j];
        float e = lrelu(AS[(size_t)s * 2 + h] + adst);
        float gv = (c < C14) ? HG[(size_t)s * 16 + c] : 0.f;
        float nm = fmaxf(m, e);
        float sc = __expf(m - nm);
        float pe = __expf(e - nm);
        ssum = ssum * sc + pe;
        acc = acc * sc + gv * pe;
        m = nm;
    }

    float v = acc / ssum + ((c < C14) ? bg[c] : 0.f);

    float vv = (c < C14) ? v : -__builtin_inff();
    float maxv = vv;
#pragma unroll
    for (int d = 1; d < 16; d <<= 1) maxv = fmaxf(maxv, __shfl_xor(maxv, d, 16));
    float ee = (c < C14) ? __expf(v - maxv) : 0.f;
    float s2 = ee;
#pragma unroll
    for (int d = 1; d < 16; d <<= 1) s2 += __shfl_xor(s2, d, 16);
    if (c < C14) out[(size_t)i * C14 + c] = v - maxv - __logf(s2);
}

// ---------------- launch ----------------

extern "C" void kernel_launch(void* const* d_in, const int* in_sizes, int n_in,
                              void* d_out, int out_size, void* d_ws, size_t ws_size,
                              hipStream_t stream) {
    const float* x       = (const float*)d_in[0];
    const int*   ei      = (const int*)d_in[1];
    const float* W1      = (const float*)d_in[2];
    const float* b1      = (const float*)d_in[3];
    const float* W2      = (const float*)d_in[4];
    const float* b2      = (const float*)d_in[5];
    const float* Wg      = (const float*)d_in[6];
    const float* att_src = (const float*)d_in[7];
    const float* att_dst = (const float*)d_in[8];
    const float* bg      = (const float*)d_in[9];

    const int N = in_sizes[0] / F_IN;
    const int E = in_sizes[1] / 2;
    const int NC1 = (F_IN + 63) / 64;   // 23
    const int NC2 = 1;

    char* p = (char*)d_ws;
    auto alloc = [&](size_t bytes) {
        char* r = p;
        p += (bytes + 255) & ~(size_t)255;
        return r;
    };
    float* h    = (float*)alloc((size_t)N * 64 * 4);
    float* g    = (float*)alloc((size_t)N * 64 * 4);
    float* hg   = (float*)alloc((size_t)N * 16 * 4);
    float* As   = (float*)alloc((size_t)N * 2 * 4);
    float* Ad   = (float*)alloc((size_t)N * 2 * 4);
    float* dinv = (float*)alloc((size_t)N * 4);
    int* cnt    = (int*)alloc((size_t)N * 4);
    int* rowst  = (int*)alloc((size_t)(N + 1) * 4);
    int* fill   = (int*)alloc((size_t)N * 4);
    int* esrc   = (int*)alloc((size_t)E * 4);
    int* bsum   = (int*)alloc(128 * 4);
    int* boff   = (int*)alloc(128 * 4);
    short* Bf1  = (short*)alloc((size_t)NC1 * 4096 * 2);
    short* Bf2  = (short*)alloc((size_t)NC2 * 4096 * 2);

    const int gN = (N + 255) / 256;
    const int gE = (E + 255) / 256;
    const int nb = (N + 1023) / 1024;
    const int g16 = (N + 15) / 16;
    const int gT64 = (N + 63) / 64;
    const int gT128 = (N + 127) / 128;

    // weight prep (frag-ordered B)
    k_prep_bf<<<(NC1 * 512 + 255) / 256, 256, 0, stream>>>(W1, Bf1, F_IN, NC1);
    k_prep_bf<<<(NC2 * 512 + 255) / 256, 256, 0, stream>>>(W2, Bf2, 64, NC2);

    // CSR by dst (real edges only; self-loops analytic)
    k_zero_int<<<gN, 256, 0, stream>>>(cnt, N);
    k_hist<<<gE, 256, 0, stream>>>(ei + E, cnt, E);
    k_dinv<<<gN, 256, 0, stream>>>(cnt, dinv, N);
    k_scan1<<<nb, 1024, 0, stream>>>(cnt, rowst, bsum, N);
    k_scan2<<<1, 128, 0, stream>>>(bsum, boff, nb);
    k_scan3<<<nb, 1024, 0, stream>>>(rowst, boff, fill, N, E);
    k_scatter<<<gE, 256, 0, stream>>>(ei, fill, esrc, E);

    // GCN layer 1 (h pre-scaled by dinv)
    gemm_mfma<<<gT128, 256, 0, stream>>>(x, F_IN, NC1, N, Bf1, dinv, h);
    gcn_prop<<<g16, 256, 0, stream>>>(h, g, rowst, esrc, dinv, b1, N);
    // GCN layer 2
    gemm_mfma<<<gT128, 256, 0, stream>>>(g, 64, NC2, N, Bf2, dinv, h);
    gcn_prop<<<g16, 256, 0, stream>>>(h, g, rowst, esrc, dinv, b2, N);
    // GAT + log_softmax
    gat_gemm<<<gT64, 256, 0, stream>>>(g, Wg, att_src, att_dst, hg, As, Ad, N);
    gat_agg<<<g16, 256, 0, stream>>>(hg, As, Ad, rowst, esrc, bg, (float*)d_out, N);
}